// Round 9
// baseline (185.437 us; speedup 1.0000x reference)
//
#include <hip/hip_runtime.h>
#include <math.h>

namespace {
constexpr int B = 32, C = 2, T = 262144, K = 6;
constexpr int NBC = B * C;          // 64 rows (b,c)
constexpr int NST = 2 * K;          // 12-dim cascade state
constexpr int PB = 8;               // blocks per row
constexpr int NW = 4;               // waves per block (256 threads)
constexpr int WPR = PB * NW;        // 32 wave-links per row
constexpr int CH = T / PB;          // 32768 samples per block
constexpr int WSP = CH / NW;        // 8192 samples per wave span
constexpr int SEGL = WSP / 64;      // 128 samples per thread-segment
constexpr int TS = 16;              // samples per staging tile
constexpr int NT = SEGL / TS;       // 8 tiles
constexpr int Q4 = SEGL / 4;        // 32 float4 per segment
constexpr int SQ1 = 7;              // A -> A^128
constexpr int SQ2 = 6;              // -> A^8192 (wave-link matrix)
constexpr float FS = 44100.0f;
// per-wave LDS arena (floats), time-overlaid (per-wave in-order LDS ops):
//   phase1: IN[64][PIN] @0 ; then FB[64][13] @0 (written after IN's last read)
//   phase2: FB @0 | SL[64][13] @832
//   phase3: IN @0 again | SO[64][PSO] @1280 (SL extracted before restaging)
constexpr int PIN = 20;
constexpr int PSO = 17;
constexpr int AFB = 0;
constexpr int ASL = 832;
constexpr int ASO = 1280;
constexpr int ARENA = ASO + 64 * PSO;   // 2368 floats = 9472 B/wave
// ws float offsets
constexpr size_t OFF_CF = 0;                  // 32*30
constexpr size_t OFF_RL = 960;                // 32*144
constexpr size_t OFF_RW = OFF_RL + 4608;      // 32*144
constexpr size_t OFF_ST = OFF_RW + 4608;      // 2048*12 link states
constexpr size_t OFF_FL = OFF_ST + 24576;     // 2048 uint flags
}

__device__ __forceinline__ float rl(float v, int lane) {
  return __int_as_float(__builtin_amdgcn_readlane(__float_as_int(v), lane));
}

// one affine-scan step: component-l lane holds s; returns (M*s)[l], M row form
__device__ __forceinline__ float mv_step(const float (&row)[NST], float sv) {
  float t0 = fmaf(row[0], rl(sv, 0), fmaf(row[1], rl(sv, 1), row[2] * rl(sv, 2)));
  float t1 = fmaf(row[3], rl(sv, 3), fmaf(row[4], rl(sv, 4), row[5] * rl(sv, 5)));
  float t2 = fmaf(row[6], rl(sv, 6), fmaf(row[7], rl(sv, 7), row[8] * rl(sv, 8)));
  float t3 = fmaf(row[9], rl(sv, 9), fmaf(row[10], rl(sv, 10), row[11] * rl(sv, 11)));
  return (t0 + t1) + (t2 + t3);
}

// Prep: per b, RBJ coeffs + A^128 / A^8192 in row-major form.
__global__ __launch_bounds__(64) void eq_prep(const float* __restrict__ fr,
                                              const float* __restrict__ gn,
                                              const float* __restrict__ qf,
                                              float* __restrict__ ws) {
  int b = blockIdx.x;
  int l = threadIdx.x;
  float* cf = ws + OFF_CF;

  float cb0[K], cb1[K], cb2[K], ca1[K], ca2[K];
#pragma unroll
  for (int k = 0; k < K; ++k) {
    float f = fr[b * K + k], g = gn[b * K + k], Q = qf[b * K + k];
    float A  = powf(10.0f, g * (1.0f / 40.0f));
    float w0 = 6.283185307179586f * f / FS;
    float cw = cosf(w0);
    float al = sinf(w0) / (2.0f * Q);
    float ia = 1.0f / (1.0f + al / A);
    cb0[k] = (1.0f + al * A) * ia;
    cb1[k] = (-2.0f * cw) * ia;
    cb2[k] = (1.0f - al * A) * ia;
    ca1[k] = (-2.0f * cw) * ia;
    ca2[k] = (1.0f - al / A) * ia;
  }
#pragma unroll
  for (int k = 0; k < K; ++k) {
    if (l == k) {
      float* p = cf + (b * K + k) * 5;
      p[0] = cb0[k]; p[1] = cb1[k]; p[2] = cb2[k]; p[3] = ca1[k]; p[4] = ca2[k];
    }
  }

  float col[NST];
  {
    float s1[K], s2[K];
#pragma unroll
    for (int k = 0; k < K; ++k) {
      s1[k] = (l == 2 * k) ? 1.0f : 0.0f;
      s2[k] = (l == 2 * k + 1) ? 1.0f : 0.0f;
    }
    float yv = 0.0f;
#pragma unroll
    for (int k = 0; k < K; ++k) {
      float yk = fmaf(cb0[k], yv, s1[k]);
      float t1 = fmaf(cb1[k], yv, s2[k]);
      float ns1 = fmaf(-ca1[k], yk, t1);
      float ns2 = fmaf(-ca2[k], yk, cb2[k] * yv);
      s1[k] = ns1; s2[k] = ns2; yv = yk;
    }
#pragma unroll
    for (int k = 0; k < K; ++k) { col[2 * k] = s1[k]; col[2 * k + 1] = s2[k]; }
  }

  auto square = [&]() {
    float nc[NST];
#pragma unroll
    for (int r = 0; r < NST; ++r) nc[r] = 0.0f;
#pragma unroll
    for (int m = 0; m < NST; ++m) {
      float wv = col[m];
#pragma unroll
      for (int r = 0; r < NST; ++r) nc[r] = fmaf(rl(col[r], m), wv, nc[r]);
    }
#pragma unroll
    for (int r = 0; r < NST; ++r) col[r] = nc[r];
  };
  auto dump = [&](float* G) {
    if (l < NST) {
#pragma unroll
      for (int r = 0; r < NST; ++r) G[(size_t)b * 144 + r * 12 + l] = col[r];
    }
  };

  for (int p = 0; p < SQ1; ++p) square();
  dump(ws + OFF_RL);
  for (int p = 0; p < SQ2; ++p) square();
  dump(ws + OFF_RW);
}

// Fused, wave-autonomous: no __syncthreads anywhere. Each wave:
// phase1 zero-state pass -> own 64-step scan -> publish bz -> lane-parallel
// flag wait + fold predecessors -> C1b incoming states -> phase3 output.
__global__ __launch_bounds__(256, 2) void eq_fused(const float* __restrict__ x,
                                                   float* __restrict__ ws,
                                                   float* __restrict__ y) {
  __shared__ __align__(16) float U[NW * ARENA];

  const float* cf = ws + OFF_CF;
  float* states = ws + OFF_ST;
  unsigned* flags = (unsigned*)(ws + OFF_FL);

  int t = threadIdx.x, w = t >> 6, l = t & 63;
  int blk = blockIdx.x, row = blk / PB, p = blk % PB, b = row >> 1;
  int wvg = p * NW + w;              // wave-link index within row [0, 32)
  int chain = row * WPR;
  bool act = (l < NST);

  float* Aw = U + w * ARENA;

  const float4* xq = reinterpret_cast<const float4*>(
      x + (size_t)row * T + (size_t)p * CH + (size_t)w * WSP);
  float4* yq = reinterpret_cast<float4*>(
      y + (size_t)row * T + (size_t)p * CH + (size_t)w * WSP);

  int sj = l >> 2, qj = l & 3;

  auto ldga = [&](float4 (&r)[4], int tt) {
#pragma unroll
    for (int j = 0; j < 4; ++j)
      r[j] = xq[(size_t)(j * 16 + sj) * Q4 + (size_t)tt * 4 + qj];
  };
  auto stage = [&](float4 (&r)[4]) {
#pragma unroll
    for (int j = 0; j < 4; ++j) {
      int seg = j * 16 + sj;
      *reinterpret_cast<float4*>(&Aw[seg * PIN + qj * 4]) = r[j];
    }
  };

  // phase-1 prologue loads first
  float4 ra[4], rb[4];
  ldga(ra, 0);
  ldga(rb, 1);

  float b0[K], b1c[K], b2c[K], a1c[K], a2c[K];
#pragma unroll
  for (int k = 0; k < K; ++k) {
    const float* cp = cf + (b * K + k) * 5;
    b0[k] = cp[0]; b1c[k] = cp[1]; b2c[k] = cp[2]; a1c[k] = cp[3]; a2c[k] = cp[4];
  }

  float s1[K], s2[K];
#pragma unroll
  for (int k = 0; k < K; ++k) { s1[k] = 0.0f; s2[k] = 0.0f; }

  auto casc8 = [&](int h) {
    float4 a = *reinterpret_cast<const float4*>(&Aw[l * PIN + h * 8]);
    float4 b4 = *reinterpret_cast<const float4*>(&Aw[l * PIN + h * 8 + 4]);
    float xs[8] = {a.x, a.y, a.z, a.w, b4.x, b4.y, b4.z, b4.w};
#pragma unroll
    for (int i = 0; i < 8; ++i) {
      float yv = xs[i];
#pragma unroll
      for (int k = 0; k < K; ++k) {
        float yk = fmaf(b0[k], yv, s1[k]);
        float t1 = fmaf(b1c[k], yv, s2[k]);
        s1[k] = fmaf(-a1c[k], yk, t1);
        s2[k] = fmaf(-a2c[k], yk, b2c[k] * yv);
        yv = yk;
      }
    }
  };
  auto casc8_out = [&](int h) {
    float4 a = *reinterpret_cast<const float4*>(&Aw[l * PIN + h * 8]);
    float4 b4 = *reinterpret_cast<const float4*>(&Aw[l * PIN + h * 8 + 4]);
    float xs[8] = {a.x, a.y, a.z, a.w, b4.x, b4.y, b4.z, b4.w};
#pragma unroll
    for (int i = 0; i < 8; ++i) {
      float yv = xs[i];
#pragma unroll
      for (int k = 0; k < K; ++k) {
        float yk = fmaf(b0[k], yv, s1[k]);
        float t1 = fmaf(b1c[k], yv, s2[k]);
        s1[k] = fmaf(-a1c[k], yk, t1);
        s2[k] = fmaf(-a2c[k], yk, b2c[k] * yv);
        yv = yk;
      }
      Aw[ASO + l * PSO + h * 8 + i] = yv;
    }
  };

  // ---- phase 1: zero-state pass over own 128-sample segment
  for (int tt = 0; tt < NT; tt += 2) {
    stage(ra);
    if (tt + 2 < NT) ldga(ra, tt + 2);
    casc8(0); casc8(1);
    stage(rb);
    if (tt + 3 < NT) ldga(rb, tt + 3);
    casc8(0); casc8(1);
  }
  // per-thread finals -> FB (after IN's last read; per-wave in-order LDS)
#pragma unroll
  for (int k = 0; k < K; ++k) {
    Aw[AFB + l * 13 + 2 * k] = s1[k];
    Aw[AFB + l * 13 + 2 * k + 1] = s2[k];
  }

  // scan matrices (phase-2 live range only)
  float rowL[NST], rowW[NST];
#pragma unroll
  for (int m = 0; m < NST; ++m) {
    rowL[m] = act ? ws[OFF_RL + (size_t)b * 144 + l * 12 + m] : 0.0f;
    rowW[m] = act ? ws[OFF_RW + (size_t)b * 144 + l * 12 + m] : 0.0f;
  }

  // ---- C1a: wave scan (zero incoming) -> own-span zero-state final bz
  float bz = 0.0f;
  for (int i = 0; i < 64; ++i) {
    float wv = act ? Aw[AFB + i * 13 + l] : 0.0f;
    bz = mv_step(rowL, bz) + wv;
  }

  // ---- publish own span (dependency-free)
  if (wvg < WPR - 1) {
    if (act)
      __hip_atomic_store((unsigned*)&states[(size_t)(chain + wvg) * NST + l],
                         __float_as_uint(bz), __ATOMIC_RELAXED,
                         __HIP_MEMORY_SCOPE_AGENT);
    if (l == 0)
      __hip_atomic_store(&flags[chain + wvg], 1u, __ATOMIC_RELEASE,
                         __HIP_MEMORY_SCOPE_AGENT);
  }

  // phase-3 prologue loads (hide L3 latency under wait/fold)
  ldga(ra, 0);
  ldga(rb, 1);

  // ---- lane-parallel flag wait (lane q watches link q), then ordered fold
  if (l < wvg) {
    while (__hip_atomic_load(&flags[chain + l], __ATOMIC_RELAXED,
                             __HIP_MEMORY_SCOPE_AGENT) == 0u)
      __builtin_amdgcn_s_sleep(1);
  }
  __threadfence();
  float bin = 0.0f;
  if (act) {
    for (int q = 0; q < wvg; ++q) {
      float bzq = __uint_as_float(__hip_atomic_load(
          (const unsigned*)&states[(size_t)(chain + q) * NST + l],
          __ATOMIC_RELAXED, __HIP_MEMORY_SCOPE_AGENT));
      bin = mv_step(rowW, bin) + bzq;
    }
  }

  // ---- C1b: true incoming per thread-segment -> SL
  {
    float sv = act ? bin : 0.0f;
    for (int i = 0; i < 64; ++i) {
      if (act) Aw[ASL + i * 13 + l] = sv;
      float wv = act ? Aw[AFB + i * 13 + l] : 0.0f;
      sv = mv_step(rowL, sv) + wv;
    }
  }
  // extract own incoming (before phase-3 staging clobbers the SL region)
  float st[NST];
#pragma unroll
  for (int r = 0; r < NST; ++r) st[r] = Aw[ASL + l * 13 + r];
#pragma unroll
  for (int k = 0; k < K; ++k) { s1[k] = st[2 * k]; s2[k] = st[2 * k + 1]; }

  // force coeff reload here (cuts phase-2 register live ranges)
  asm volatile("" ::: "memory");
#pragma unroll
  for (int k = 0; k < K; ++k) {
    const float* cp = cf + (b * K + k) * 5;
    b0[k] = cp[0]; b1c[k] = cp[1]; b2c[k] = cp[2]; a1c[k] = cp[3]; a2c[k] = cp[4];
  }

  // ---- phase 3: exact pass, outputs staged to SO, flushed as full lines
  auto flush = [&](int tt) {
#pragma unroll
    for (int j = 0; j < 4; ++j) {
      int seg = j * 16 + sj;
      float4 o;
      o.x = Aw[ASO + seg * PSO + qj * 4 + 0];
      o.y = Aw[ASO + seg * PSO + qj * 4 + 1];
      o.z = Aw[ASO + seg * PSO + qj * 4 + 2];
      o.w = Aw[ASO + seg * PSO + qj * 4 + 3];
      yq[(size_t)seg * Q4 + (size_t)tt * 4 + qj] = o;
    }
  };

  for (int tt = 0; tt < NT; tt += 2) {
    stage(ra);
    if (tt + 2 < NT) ldga(ra, tt + 2);
    casc8_out(0); casc8_out(1);
    flush(tt);
    stage(rb);
    if (tt + 3 < NT) ldga(rb, tt + 3);
    casc8_out(0); casc8_out(1);
    flush(tt + 1);
  }
}

extern "C" void kernel_launch(void* const* d_in, const int* in_sizes, int n_in,
                              void* d_out, int out_size, void* d_ws, size_t ws_size,
                              hipStream_t stream) {
  const float* audio = (const float*)d_in[0];
  const float* fr    = (const float*)d_in[1];
  const float* gn    = (const float*)d_in[2];
  const float* qf    = (const float*)d_in[3];
  float* out = (float*)d_out;
  float* ws = (float*)d_ws;

  hipMemsetAsync((char*)d_ws + OFF_FL * sizeof(float), 0,
                 NBC * WPR * sizeof(unsigned), stream);
  hipLaunchKernelGGL(eq_prep, dim3(B), dim3(64), 0, stream, fr, gn, qf, ws);
  hipLaunchKernelGGL(eq_fused, dim3(NBC * PB), dim3(256), 0, stream,
                     audio, ws, out);
}

// Round 10
// 87.259 us; speedup vs baseline: 2.1251x; 2.1251x over previous
//
#include <hip/hip_runtime.h>
#include <math.h>

namespace {
constexpr int B = 32, C = 2, T = 262144, K = 6;
constexpr int SEG = 2048;         // segments per (b,c)
constexpr int L = T / SEG;        // 128 samples per segment
constexpr int NBC = B * C;        // 64 sequences
constexpr int NST = 2 * K;        // 12-dim cascade state
constexpr int LOG2L = 7;          // L = 2^7
constexpr int TS = 16;            // samples per staging tile
constexpr int NT = L / TS;        // 8 tiles
constexpr int WPB = SEG / 64;     // 32 one-wave blocks per (b,c)
constexpr int GP = 8;             // segments per scan thread
constexpr int NW = 4;             // scan waves per block (256 threads)
constexpr float FS = 44100.0f;
}

__device__ __forceinline__ float rl(float v, int lane) {
  return __int_as_float(__builtin_amdgcn_readlane(__float_as_int(v), lane));
}

__device__ __forceinline__ void ld12(const float* p, float (&v)[NST]) {
  const float4* q = reinterpret_cast<const float4*>(p);
  float4 a = q[0], b4 = q[1], c4 = q[2];
  v[0] = a.x; v[1] = a.y; v[2] = a.z; v[3] = a.w;
  v[4] = b4.x; v[5] = b4.y; v[6] = b4.z; v[7] = b4.w;
  v[8] = c4.x; v[9] = c4.y; v[10] = c4.z; v[11] = c4.w;
}

__device__ __forceinline__ void st12(float* p, const float (&v)[NST]) {
  float4* q = reinterpret_cast<float4*>(p);
  q[0] = make_float4(v[0], v[1], v[2], v[3]);
  q[1] = make_float4(v[4], v[5], v[6], v[7]);
  q[2] = make_float4(v[8], v[9], v[10], v[11]);
}

// s = M*s + z (12x12 affine step, fully register-resident)
__device__ __forceinline__ void affine(const float (&M)[NST][NST], float (&s)[NST],
                                       const float (&z)[NST]) {
  float ns[NST];
#pragma unroll
  for (int r = 0; r < NST; ++r) {
    float a = z[r];
#pragma unroll
    for (int m = 0; m < NST; ++m) a = fmaf(M[r][m], s[m], a);
    ns[r] = a;
  }
#pragma unroll
  for (int r = 0; r < NST; ++r) s[r] = ns[r];
}

// K1: RBJ peaking-EQ coefficients, normalized by a0. cf[(b*K+k)*5 + ...]
__global__ void eq_coeffs(const float* __restrict__ fr, const float* __restrict__ gn,
                          const float* __restrict__ qf, float* __restrict__ cf) {
  int i = blockIdx.x * blockDim.x + threadIdx.x;
  if (i >= B * K) return;
  float f = fr[i], g = gn[i], Q = qf[i];
  float A  = powf(10.0f, g * (1.0f / 40.0f));
  float w0 = 6.283185307179586f * f / FS;
  float cw = cosf(w0);
  float al = sinf(w0) / (2.0f * Q);
  float b0 = 1.0f + al * A;
  float b1 = -2.0f * cw;
  float b2 = 1.0f - al * A;
  float a0 = 1.0f + al / A;
  float a2 = 1.0f - al / A;
  float ia = 1.0f / a0;
  float* p = cf + i * 5;
  p[0] = b0 * ia; p[1] = b1 * ia; p[2] = b2 * ia; p[3] = b1 * ia; p[4] = a2 * ia;
}

// Segment pass, 1 wave per block, LDS transpose-staged I/O, depth-2 prefetch.
template <bool WRITE_OUT>
__global__ __launch_bounds__(64, 2) void eq_pass(const float* __restrict__ x,
                                                 const float* __restrict__ cf,
                                                 const float* __restrict__ st_in,
                                                 float* __restrict__ st_out,
                                                 float* __restrict__ y) {
  __shared__ float sIn[2][64][17];
  __shared__ float sOut[2][64][17];

  int l = threadIdx.x;
  int wid = blockIdx.x;           // 0 .. NBC*WPB-1
  int bc = wid / WPB;
  int segbase = (wid % WPB) * 64;
  int b = bc / C;
  int tid = bc * SEG + segbase + l;

  const float4* xp4 = reinterpret_cast<const float4*>(x + (size_t)bc * T + (size_t)segbase * L);
  float4* yp4 = reinterpret_cast<float4*>(y + (size_t)bc * T + (size_t)segbase * L);
  constexpr int Q4 = L / 4;  // 32 float4 per segment

  int sj = l >> 2;   // staging sub-segment 0..15
  int qj = l & 3;    // 16B quarter of the 64B line

  // prologue loads first (hide cf/state loads under them)
  float4 ra[4], rb[4];
#pragma unroll
  for (int j = 0; j < 4; ++j) ra[j] = xp4[(size_t)(j * 16 + sj) * Q4 + qj];
#pragma unroll
  for (int j = 0; j < 4; ++j) rb[j] = xp4[(size_t)(j * 16 + sj) * Q4 + 4 + qj];

  float b0[K], b1c[K], b2c[K], a1c[K], a2c[K];
#pragma unroll
  for (int k = 0; k < K; ++k) {
    const float* p = cf + (b * K + k) * 5;
    b0[k] = p[0]; b1c[k] = p[1]; b2c[k] = p[2]; a1c[k] = p[3]; a2c[k] = p[4];
  }

  float s1[K], s2[K];
  if (WRITE_OUT) {
    float st[NST];
    ld12(st_in + (size_t)tid * NST, st);
#pragma unroll
    for (int k = 0; k < K; ++k) { s1[k] = st[2 * k]; s2[k] = st[2 * k + 1]; }
  } else {
#pragma unroll
    for (int k = 0; k < K; ++k) { s1[k] = 0.0f; s2[k] = 0.0f; }
  }

  auto tile = [&](float4 (&r)[4], int t, int pb) {
    // stage tile t (regs -> LDS, transposed)
#pragma unroll
    for (int j = 0; j < 4; ++j) {
      int seg = j * 16 + sj;
      sIn[pb][seg][qj * 4 + 0] = r[j].x;
      sIn[pb][seg][qj * 4 + 1] = r[j].y;
      sIn[pb][seg][qj * 4 + 2] = r[j].z;
      sIn[pb][seg][qj * 4 + 3] = r[j].w;
    }
    // issue loads for tile t+2
    if (t + 2 < NT) {
#pragma unroll
      for (int j = 0; j < 4; ++j)
        r[j] = xp4[(size_t)(j * 16 + sj) * Q4 + (size_t)(t + 2) * 4 + qj];
    }
    // own segment: 16 sequential samples through the 6-stage cascade
    float out16[TS];
#pragma unroll
    for (int i = 0; i < TS; ++i) {
      float yv = sIn[pb][l][i];
#pragma unroll
      for (int k = 0; k < K; ++k) {
        float yk = fmaf(b0[k], yv, s1[k]);
        float t1 = fmaf(b1c[k], yv, s2[k]);
        s1[k] = fmaf(-a1c[k], yk, t1);
        float t2 = b2c[k] * yv;
        s2[k] = fmaf(-a2c[k], yk, t2);
        yv = yk;
      }
      out16[i] = yv;
    }
    if (WRITE_OUT) {
#pragma unroll
      for (int i = 0; i < TS; ++i) sOut[pb][l][i] = out16[i];
      // flush as full 64B lines
#pragma unroll
      for (int j = 0; j < 4; ++j) {
        int seg = j * 16 + sj;
        float4 o;
        o.x = sOut[pb][seg][qj * 4 + 0];
        o.y = sOut[pb][seg][qj * 4 + 1];
        o.z = sOut[pb][seg][qj * 4 + 2];
        o.w = sOut[pb][seg][qj * 4 + 3];
        yp4[(size_t)seg * Q4 + (size_t)t * 4 + qj] = o;
      }
    }
  };

  for (int tt = 0; tt < NT; tt += 2) {
    tile(ra, tt, 0);
    tile(rb, tt + 1, 1);
  }

  if (!WRITE_OUT) {
    float st[NST];
#pragma unroll
    for (int k = 0; k < K; ++k) { st[2 * k] = s1[k]; st[2 * k + 1] = s2[k]; }
    st12(st_out + (size_t)tid * NST, st);
  }
}

// K3: hierarchical scan, 256 threads (4 waves) per (b,c).
// Thread t owns GP=8 segments. Phase A: squaring chain A -> Phi=A^L ->
// Phi_g=A^(GP*L) -> Phi_w=Phi_g^64. Phase B: per-thread zero-incoming group
// final (Phi replicated in VGPRs). C1a: 64-step wave serial scan -> wave
// final. C2: block scan with Phi_w. C1b: re-scan from true incoming. Phase D:
// per-thread replay emits per-segment incoming states.
__global__ __launch_bounds__(256, 1) void eq_scan(const float* __restrict__ cf,
                                                  const float* __restrict__ zsf,
                                                  float* __restrict__ sif) {
  __shared__ float PhiL[NST][NST];
  __shared__ float Rg[NST][NST + 1];
  __shared__ float Rw[NST][NST + 1];
  __shared__ float FB[NW][64][NST + 1];
  __shared__ float SL[NW][64][NST + 1];
  __shared__ float WF[NW][NST + 1];

  int bc = blockIdx.x;
  int b = bc / C;
  int t = threadIdx.x;
  int w = t >> 6;
  int l = t & 63;
  bool act = (l < NST);

  float b0[K], b1c[K], b2c[K], a1c[K], a2c[K];
#pragma unroll
  for (int k = 0; k < K; ++k) {
    const float* p = cf + (b * K + k) * 5;
    b0[k] = p[0]; b1c[k] = p[1]; b2c[k] = p[2]; a1c[k] = p[3]; a2c[k] = p[4];
  }

  // column l of the one-sample homogeneous map A
  float col[NST];
  {
    float s1[K], s2[K];
#pragma unroll
    for (int k = 0; k < K; ++k) {
      s1[k] = (l == 2 * k) ? 1.0f : 0.0f;
      s2[k] = (l == 2 * k + 1) ? 1.0f : 0.0f;
    }
    float yv = 0.0f;
#pragma unroll
    for (int k = 0; k < K; ++k) {
      float yk = fmaf(b0[k], yv, s1[k]);
      float t1 = fmaf(b1c[k], yv, s2[k]);
      float ns1 = fmaf(-a1c[k], yk, t1);
      float ns2 = fmaf(-a2c[k], yk, b2c[k] * yv);
      s1[k] = ns1; s2[k] = ns2; yv = yk;
    }
#pragma unroll
    for (int k = 0; k < K; ++k) { col[2 * k] = s1[k]; col[2 * k + 1] = s2[k]; }
  }

  auto square = [&]() {
    float nc[NST];
#pragma unroll
    for (int r = 0; r < NST; ++r) nc[r] = 0.0f;
#pragma unroll
    for (int m = 0; m < NST; ++m) {
      float wv = col[m];
#pragma unroll
      for (int r = 0; r < NST; ++r) nc[r] = fmaf(rl(col[r], m), wv, nc[r]);
    }
#pragma unroll
    for (int r = 0; r < NST; ++r) col[r] = nc[r];
  };

  for (int p = 0; p < LOG2L; ++p) square();          // Phi = A^128
  if (w == 0 && act) {
#pragma unroll
    for (int r = 0; r < NST; ++r) PhiL[r][l] = col[r];
  }
  for (int p = 0; p < 3; ++p) square();              // Phi_g = A^1024
  if (w == 0 && act) {
#pragma unroll
    for (int r = 0; r < NST; ++r) Rg[r][l] = col[r];
  }
  for (int p = 0; p < 6; ++p) square();              // Phi_w = A^65536
  if (w == 0 && act) {
#pragma unroll
    for (int r = 0; r < NST; ++r) Rw[r][l] = col[r];
  }
  __syncthreads();

  float rowg[NST], roww[NST];
#pragma unroll
  for (int m = 0; m < NST; ++m) {
    rowg[m] = act ? Rg[l][m] : 0.0f;
    roww[m] = act ? Rw[l][m] : 0.0f;
  }
  float phi[NST][NST];
#pragma unroll
  for (int r = 0; r < NST; ++r)
#pragma unroll
    for (int m = 0; m < NST; ++m) phi[r][m] = PhiL[r][m];

  // Phase B: zero-incoming final over this thread's GP segments
  const float* zb = zsf + ((size_t)bc * SEG + (size_t)t * GP) * NST;
  float s[NST];
  ld12(zb, s);
#pragma unroll
  for (int j = 1; j < GP; ++j) {
    float zc[NST];
    ld12(zb + (size_t)j * NST, zc);
    affine(phi, s, zc);
  }
#pragma unroll
  for (int r = 0; r < NST; ++r) FB[w][l][r] = s[r];
  __syncthreads();

  // C1a: wave serial scan (zero incoming) -> wave final
  {
    float sv = 0.0f;
    for (int i = 0; i < 64; ++i) {
      float wv = act ? FB[w][i][l] : 0.0f;
      float t0 = fmaf(rowg[0], rl(sv, 0), fmaf(rowg[1], rl(sv, 1), rowg[2] * rl(sv, 2)));
      float t1 = fmaf(rowg[3], rl(sv, 3), fmaf(rowg[4], rl(sv, 4), rowg[5] * rl(sv, 5)));
      float t2 = fmaf(rowg[6], rl(sv, 6), fmaf(rowg[7], rl(sv, 7), rowg[8] * rl(sv, 8)));
      float t3 = fmaf(rowg[9], rl(sv, 9), fmaf(rowg[10], rl(sv, 10), rowg[11] * rl(sv, 11)));
      sv = ((t0 + t1) + (t2 + t3)) + wv;
    }
    if (act) WF[w][l] = sv;
  }
  __syncthreads();

  // C2: block scan over wave finals (wave w folds w steps)
  float swv = 0.0f;
  for (int w2 = 0; w2 < w; ++w2) {
    float wfv = act ? WF[w2][l] : 0.0f;
    float t0 = fmaf(roww[0], rl(swv, 0), fmaf(roww[1], rl(swv, 1), roww[2] * rl(swv, 2)));
    float t1 = fmaf(roww[3], rl(swv, 3), fmaf(roww[4], rl(swv, 4), roww[5] * rl(swv, 5)));
    float t2 = fmaf(roww[6], rl(swv, 6), fmaf(roww[7], rl(swv, 7), roww[8] * rl(swv, 8)));
    float t3 = fmaf(roww[9], rl(swv, 9), fmaf(roww[10], rl(swv, 10), roww[11] * rl(swv, 11)));
    swv = ((t0 + t1) + (t2 + t3)) + wfv;
  }

  // C1b: re-scan from true wave incoming; store per-group incoming states
  {
    float sv = swv;
    for (int i = 0; i < 64; ++i) {
      if (act) SL[w][i][l] = sv;
      float wv = act ? FB[w][i][l] : 0.0f;
      float t0 = fmaf(rowg[0], rl(sv, 0), fmaf(rowg[1], rl(sv, 1), rowg[2] * rl(sv, 2)));
      float t1 = fmaf(rowg[3], rl(sv, 3), fmaf(rowg[4], rl(sv, 4), rowg[5] * rl(sv, 5)));
      float t2 = fmaf(rowg[6], rl(sv, 6), fmaf(rowg[7], rl(sv, 7), rowg[8] * rl(sv, 8)));
      float t3 = fmaf(rowg[9], rl(sv, 9), fmaf(rowg[10], rl(sv, 10), rowg[11] * rl(sv, 11)));
      sv = ((t0 + t1) + (t2 + t3)) + wv;
    }
  }
  __syncthreads();

  // Phase D: replay — emit incoming state of each owned segment
  float sg[NST];
#pragma unroll
  for (int r = 0; r < NST; ++r) sg[r] = SL[w][l][r];
  float* ob = sif + ((size_t)bc * SEG + (size_t)t * GP) * NST;
#pragma unroll
  for (int j = 0; j < GP; ++j) {
    st12(ob + (size_t)j * NST, sg);
    if (j + 1 < GP) {
      float zc[NST];
      ld12(zb + (size_t)j * NST, zc);
      affine(phi, sg, zc);
    }
  }
}

extern "C" void kernel_launch(void* const* d_in, const int* in_sizes, int n_in,
                              void* d_out, int out_size, void* d_ws, size_t ws_size,
                              hipStream_t stream) {
  const float* audio = (const float*)d_in[0];
  const float* fr    = (const float*)d_in[1];
  const float* gn    = (const float*)d_in[2];
  const float* qf    = (const float*)d_in[3];
  float* out = (float*)d_out;

  // ws layout (floats): coeffs | zero-state finals | incoming states
  float* cf  = (float*)d_ws;                    // B*K*5 = 960
  float* zsf = cf + B * K * 5;                  // NBC*SEG*NST = 1572864
  float* sif = zsf + (size_t)NBC * SEG * NST;   // 1572864

  hipLaunchKernelGGL(eq_coeffs, dim3((B * K + 63) / 64), dim3(64), 0, stream,
                     fr, gn, qf, cf);
  hipLaunchKernelGGL((eq_pass<false>), dim3(NBC * WPB), dim3(64), 0, stream,
                     audio, cf, nullptr, zsf, out);
  hipLaunchKernelGGL(eq_scan, dim3(NBC), dim3(256), 0, stream, cf, zsf, sif);
  hipLaunchKernelGGL((eq_pass<true>), dim3(NBC * WPB), dim3(64), 0, stream,
                     audio, cf, sif, nullptr, out);
}